// Round 6
// baseline (650.333 us; speedup 1.0000x reference)
//
#include <hip/hip_runtime.h>

// ---------------------------------------------------------------------------
// DenseLanguageGuidanceModule on MI355X (gfx950)
// bf16 hi/lo split GEMMs (x3 MFMA, fp32 accumulate) for ~fp32 accuracy.
// Round 6: single-buffer 32KB (BK=32) m97-style loop -> 5 blocks/CU;
// A(t+1) reg-prefetch under compute; B via global_load_lds; BN=64 tile
// variant for the small grid GEMMs (K3/K5/S/T). XCD swizzle kept on K2f.
// ---------------------------------------------------------------------------

using s16x8  = __attribute__((ext_vector_type(8))) short;
using f32x4v = __attribute__((ext_vector_type(4))) float;

__device__ __forceinline__ unsigned short f2bf(float f) {
  unsigned int u = __float_as_uint(f);
  u += 0x7fffu + ((u >> 16) & 1u);     // RNE
  return (unsigned short)(u >> 16);
}
__device__ __forceinline__ float bf2f(unsigned short h) {
  return __uint_as_float(((unsigned int)h) << 16);
}
__device__ __forceinline__ void split2(float v, unsigned short &hh, unsigned short &ll) {
  hh = f2bf(v);
  ll = f2bf(v - bf2f(hh));
}
__device__ __forceinline__ void split8v(float4 a, float4 b, s16x8& H, s16x8& L) {
  unsigned short hh, ll;
  split2(a.x, hh, ll); H[0] = (short)hh; L[0] = (short)ll;
  split2(a.y, hh, ll); H[1] = (short)hh; L[1] = (short)ll;
  split2(a.z, hh, ll); H[2] = (short)hh; L[2] = (short)ll;
  split2(a.w, hh, ll); H[3] = (short)hh; L[3] = (short)ll;
  split2(b.x, hh, ll); H[4] = (short)hh; L[4] = (short)ll;
  split2(b.y, hh, ll); H[5] = (short)hh; L[5] = (short)ll;
  split2(b.z, hh, ll); H[6] = (short)hh; L[6] = (short)ll;
  split2(b.w, hh, ll); H[7] = (short)hh; L[7] = (short)ll;
}

// async global->LDS, 16B per lane; LDS dest is wave-uniform base + lane*16
__device__ __forceinline__ void gload16(const unsigned short* g, unsigned short* l) {
  __builtin_amdgcn_global_load_lds(
      (const __attribute__((address_space(1))) unsigned int*)(const void*)g,
      (__attribute__((address_space(3))) unsigned int*)(void*)l,
      16, 0, 0);
}

// transpose W[K][N] -> Wt[N][Kpad] bf16 hi/lo, zero-pad k >= K
__global__ __launch_bounds__(256) void prep_weight(const float* __restrict__ W,
                                                   unsigned short* __restrict__ Wh,
                                                   unsigned short* __restrict__ Wl,
                                                   int K, int N, int Kpad) {
  __shared__ float tile[32][33];
  int nb = blockIdx.x * 32, kb = blockIdx.y * 32;
  int tx = threadIdx.x & 31, ty = threadIdx.x >> 5;   // 32 x 8
  #pragma unroll
  for (int i = 0; i < 32; i += 8) {
    int k = kb + ty + i, n = nb + tx;
    tile[ty + i][tx] = (k < K && n < N) ? W[(long)k * N + n] : 0.f;
  }
  __syncthreads();
  #pragma unroll
  for (int i = 0; i < 32; i += 8) {
    int n = nb + ty + i, k = kb + tx;
    if (n < N && k < Kpad) {
      unsigned short hh, ll;
      split2(tile[tx][ty + i], hh, ll);
      Wh[(long)n * Kpad + k] = hh;
      Wl[(long)n * Kpad + k] = ll;
    }
  }
}

// ---------------- generic NT GEMM, bf16 hi/lo x3, single-buffer BK=32 -------
// C[m][n] = sum_k A[m][k] * Bt[n][k]
// A: raw fp32 (AF32: reg prefetch + in-register split + swizzled ds_write)
//    or pre-split bf16 pair (DMA via global_load_lds, source-XOR swizzle).
// B: always pre-split pair, DMA.
// Tile 128 x (NJ*32), BK=32, 256 threads (4 waves 2x2).
// LDS single buffer: Ah | Al | Bh | Bl. 24-32KB -> 4-5 blocks/CU.
struct GemmArgs {
  const unsigned short *Ah, *Alo, *Bh, *Blo;
  const float *Af;  // fp32 A source (when AF32)
  int K;            // multiple of 32
  int Mld, Nld;     // row clamp bounds
  int lda, ldb;     // row strides (elements)
  long long sA, sB; // batch strides (elements)
};

template <bool AF32, bool SWZ, int NJ, class Epi>
__global__ __launch_bounds__(256, 4) void gemm3(GemmArgs g, Epi epi) {
  constexpr int BN  = NJ * 32;
  constexpr int ASZ = 128 * 32;        // shorts per A component
  constexpr int BSZ = BN * 32;         // shorts per B component
  __shared__ __align__(16) unsigned short sm[2 * ASZ + 2 * BSZ];
  unsigned short* sAh = sm;
  unsigned short* sAl = sm + ASZ;
  unsigned short* sBh = sm + 2 * ASZ;
  unsigned short* sBl = sm + 2 * ASZ + BSZ;

  int bidx = blockIdx.x, bidy = blockIdx.y;
  if constexpr (SWZ) {   // XCD-contiguous remap (requires nwg % 8 == 0)
    int nx = gridDim.x;
    int nwg = nx * gridDim.y;
    int orig = bidx + bidy * nx;
    int swz = (orig & 7) * (nwg >> 3) + (orig >> 3);
    bidx = swz % nx; bidy = swz / nx;
  }

  const int t    = threadIdx.x;
  const int b    = blockIdx.z;
  const int m0   = bidy * 128;
  const int n0   = bidx * BN;
  const int lane = t & 63;
  const int w    = t >> 6;
  const int wr   = (w >> 1) * 64;
  const int wc   = (w & 1) * (NJ * 16);

  const long long aBase = (long long)b * g.sA;
  const long long bBase = (long long)b * g.sB;

  // ---- DMA staging coords ----
  const int clk = lane & 3;
  // B rows: NJ==4 -> wave w stages rows [w*32,w*32+32) (2 loads);
  //         NJ==2 -> rows [w*16,w*16+16) (1 load)
  const int rwB = (NJ == 4) ? ((w << 5) + (lane >> 2)) : ((w << 4) + (lane >> 2));
  const int sckB = ((clk ^ ((rwB >> 1) & 3)) << 3);    // swizzled source chunk
  int br0 = n0 + rwB;      if (br0 > g.Nld - 1) br0 = g.Nld - 1;
  int br1 = n0 + rwB + 16; if (br1 > g.Nld - 1) br1 = g.Nld - 1;
  const long long bR0d = bBase + (long long)br0 * g.ldb + sckB;
  const long long bR1d = bBase + (long long)br1 * g.ldb + sckB;
  const int dB0 = (NJ == 4) ? (w << 10) : (w << 9);
  const int dB1 = dB0 + 512;                            // only NJ==4
  // A rows (DMA path): wave w stages rows [w*32, w*32+32)
  const int rwA = (w << 5) + (lane >> 2);
  const int sckA = ((clk ^ ((rwA >> 1) & 3)) << 3);
  int arD0 = m0 + rwA;      if (arD0 > g.Mld - 1) arD0 = g.Mld - 1;
  int arD1 = m0 + rwA + 16; if (arD1 > g.Mld - 1) arD1 = g.Mld - 1;
  const long long aR0d = aBase + (long long)arD0 * g.lda + sckA;
  const long long aR1d = aBase + (long long)arD1 * g.lda + sckA;
  const int dA0 = w << 10, dA1 = (w << 10) + 512;

  // ---- AF32 reg-staging coords (swizzled ds_write) ----
  const int rA0 = t >> 2, rA1 = 64 + (t >> 2), cc = t & 3;
  const int cOff = cc << 3;
  int mr0 = m0 + rA0; if (mr0 > g.Mld - 1) mr0 = g.Mld - 1;
  int mr1 = m0 + rA1; if (mr1 > g.Mld - 1) mr1 = g.Mld - 1;
  const long long aR0 = aBase + (long long)mr0 * g.lda;
  const long long aR1 = aBase + (long long)mr1 * g.lda;
  const int wA0 = rA0 * 32 + ((cc ^ ((rA0 >> 1) & 3)) << 3);
  const int wA1 = rA1 * 32 + ((cc ^ ((rA1 >> 1) & 3)) << 3);

  // read-fragment offsets
  int roffA[4], roffB[NJ];
  #pragma unroll
  for (int i = 0; i < 4; ++i) {
    int row = wr + i * 16 + (lane & 15);
    int ch  = lane >> 4;
    roffA[i] = row * 32 + ((ch ^ ((row >> 1) & 3)) << 3);
  }
  #pragma unroll
  for (int j = 0; j < NJ; ++j) {
    int row = wc + j * 16 + (lane & 15);
    int ch  = lane >> 4;
    roffB[j] = row * 32 + ((ch ^ ((row >> 1) & 3)) << 3);
  }

  f32x4v acc[4][NJ];
  #pragma unroll
  for (int i = 0; i < 4; ++i)
    #pragma unroll
    for (int j = 0; j < NJ; ++j)
      #pragma unroll
      for (int r = 0; r < 4; ++r) acc[i][j][r] = 0.f;

  float4 pa0, pa1, pa2, pa3;   // AF32 prefetch regs

  auto issueDMA = [&](int k0) {
    gload16(g.Bh  + (bR0d + k0), sBh + dB0);
    gload16(g.Blo + (bR0d + k0), sBl + dB0);
    if constexpr (NJ == 4) {
      gload16(g.Bh  + (bR1d + k0), sBh + dB1);
      gload16(g.Blo + (bR1d + k0), sBl + dB1);
    }
    if constexpr (!AF32) {
      gload16(g.Ah  + (aR0d + k0), sAh + dA0);
      gload16(g.Ah  + (aR1d + k0), sAh + dA1);
      gload16(g.Alo + (aR0d + k0), sAl + dA0);
      gload16(g.Alo + (aR1d + k0), sAl + dA1);
    }
  };
  auto issueA = [&](int k0) {
    if constexpr (AF32) {
      const float* s0 = g.Af + (aR0 + k0 + cOff);
      const float* s1 = g.Af + (aR1 + k0 + cOff);
      pa0 = *(const float4*)s0; pa1 = *(const float4*)(s0 + 4);
      pa2 = *(const float4*)s1; pa3 = *(const float4*)(s1 + 4);
    }
  };
  auto writeA = [&]() {
    if constexpr (AF32) {
      s16x8 H, L;
      split8v(pa0, pa1, H, L);
      *(s16x8*)(sAh + wA0) = H; *(s16x8*)(sAl + wA0) = L;
      split8v(pa2, pa3, H, L);
      *(s16x8*)(sAh + wA1) = H; *(s16x8*)(sAl + wA1) = L;
    }
  };

  // prologue: stage tile 0
  issueDMA(0);
  if constexpr (AF32) { issueA(0); writeA(); }
  const int nkt = g.K >> 5;
  for (int kt = 0; kt < nkt; ++kt) {
    asm volatile("s_waitcnt vmcnt(0)" ::: "memory");  // DMA landed
    __syncthreads();                                  // + all A ds_writes visible
    if (AF32 && kt + 1 < nkt) issueA((kt + 1) << 5);  // fp32 loads fly under compute
    s16x8 ah[4], al[4], bh[NJ], bl[NJ];
    #pragma unroll
    for (int i = 0; i < 4; ++i) {
      ah[i] = *(const s16x8*)(sAh + roffA[i]);
      al[i] = *(const s16x8*)(sAl + roffA[i]);
    }
    #pragma unroll
    for (int j = 0; j < NJ; ++j) {
      bh[j] = *(const s16x8*)(sBh + roffB[j]);
      bl[j] = *(const s16x8*)(sBl + roffB[j]);
    }
    #pragma unroll
    for (int i = 0; i < 4; ++i)
      #pragma unroll
      for (int j = 0; j < NJ; ++j) {
        acc[i][j] = __builtin_amdgcn_mfma_f32_16x16x32_bf16(ah[i], bh[j], acc[i][j], 0, 0, 0);
        acc[i][j] = __builtin_amdgcn_mfma_f32_16x16x32_bf16(ah[i], bl[j], acc[i][j], 0, 0, 0);
        acc[i][j] = __builtin_amdgcn_mfma_f32_16x16x32_bf16(al[i], bh[j], acc[i][j], 0, 0, 0);
      }
    __syncthreads();                                  // buffer free for next tile
    if (kt + 1 < nkt) {
      writeA();                                       // regs arrived during compute
      issueDMA((kt + 1) << 5);
    }
  }
  // epilogue: D row=(lane>>4)*4+r, col=lane&15
  #pragma unroll
  for (int i = 0; i < 4; ++i)
    #pragma unroll
    for (int j = 0; j < NJ; ++j) {
      int mm = m0 + wr + i * 16 + ((lane >> 4) << 2);
      int nn = n0 + wc + j * 16 + (lane & 15);
      epi(b, mm, nn, acc[i][j]);
    }
}

// ---------------- epilogues ----------------
struct EpiBF16Pair {   // out[b][m][n] bf16 hi/lo pair (+optional bias)
  unsigned short *h, *lo; const float* bias; long long bs; int ld; int Mst;
  __device__ void operator()(int b, int m, int n, f32x4v v) const {
    float bb = bias ? bias[n] : 0.f;
    #pragma unroll
    for (int r = 0; r < 4; ++r) {
      int mm = m + r;
      if (mm < Mst) {
        long long o = (long long)b * bs + (long long)mm * ld + n;
        unsigned short hh, ll;
        split2(v[r] + bb, hh, ll);
        h[o] = hh; lo[o] = ll;
      }
    }
  }
};

struct EpiDualL {      // K1f: n<512 -> fkl[m][n]; n>=512 -> fvl[m][n-512]
  unsigned short *kh, *kl, *vh, *vl; const float *bk, *bv;
  __device__ void operator()(int, int m, int n, f32x4v v) const {
    bool lo512 = n < 512;
    float bb = lo512 ? bk[n] : bv[n - 512];
    int nn = lo512 ? n : n - 512;
    unsigned short* H = lo512 ? kh : vh;
    unsigned short* L = lo512 ? kl : vl;
    #pragma unroll
    for (int r = 0; r < 4; ++r) {
      int mm = m + r;
      if (mm < 2464) {
        long long o = (long long)mm * 512 + nn;
        unsigned short hh, ll;
        split2(v[r] + bb, hh, ll);
        H[o] = hh; L[o] = ll;
      }
    }
  }
};

struct EpiDualV {      // K2f: n<512 -> fkv[m][n]; n>=512 -> fvvT[b2][n-512][v]
  unsigned short *kh, *kl, *vh, *vl; const float *bk, *bv;
  __device__ void operator()(int, int m, int n, f32x4v v) const {
    if (n < 512) {
      float bb = bk[n];
      #pragma unroll
      for (int r = 0; r < 4; ++r) {
        long long o = (long long)(m + r) * 512 + n;
        unsigned short hh, ll;
        split2(v[r] + bb, hh, ll);
        kh[o] = hh; kl[o] = ll;
      }
    } else {
      int b2 = m >> 10, vv = m & 1023;
      float bb = bv[n - 512];
      ushort4 H, L;
      split2(v[0] + bb, H.x, L.x); split2(v[1] + bb, H.y, L.y);
      split2(v[2] + bb, H.z, L.z); split2(v[3] + bb, H.w, L.w);
      long long o = ((long long)b2 * 512 + (n - 512)) * 1024 + vv;
      *(ushort4*)(vh + o) = H;
      *(ushort4*)(vl + o) = L;
    }
  }
};

struct EpiScore {      // K3: a_raw[b][m][n] fp32, scaled, m<77
  float* out;
  __device__ void operator()(int b, int m, int n, f32x4v v) const {
    #pragma unroll
    for (int r = 0; r < 4; ++r) {
      int mm = m + r;
      if (mm < 77)
        out[((long long)b * 77 + mm) * 1024 + n] = v[r] * 0.04419417382415922f;
    }
  }
};

struct EpiTransT {     // T-gemm: T_t[b][o=n][l=m+r], zero l>=77
  unsigned short *h, *lo;
  __device__ void operator()(int b, int m, int n, f32x4v v) const {
    #pragma unroll
    for (int r = 0; r < 4; ++r) {
      int mm = m + r;
      float val = (mm < 77) ? v[r] : 0.f;
      long long o = (long long)b * 98304 + (long long)n * 128 + mm;
      unsigned short hh, ll;
      split2(val, hh, ll);
      h[o] = hh; lo[o] = ll;
    }
  }
};

struct EpiOutB {       // OUT: d_out[b*1024+m][768] fp32 + b_m
  float* out; const float* bias;
  __device__ void operator()(int b, int m, int n, f32x4v v) const {
    float bb = bias[n];
    #pragma unroll
    for (int r = 0; r < 4; ++r)
      out[(long long)(b * 1024 + m + r) * 768 + n] = v[r] + bb;
  }
};

// ---------------- softmax over Nv (rows of a_raw) ----------------
__global__ __launch_bounds__(256) void softmax_rows(const float* __restrict__ a,
                                                    unsigned short* __restrict__ Ph,
                                                    unsigned short* __restrict__ Plo) {
  long row = blockIdx.x;                 // (b*77+l)
  const float* src = a + row * 1024;
  int t = threadIdx.x;
  float4 x = ((const float4*)src)[t];
  float mx = fmaxf(fmaxf(x.x, x.y), fmaxf(x.z, x.w));
  #pragma unroll
  for (int o = 32; o; o >>= 1) mx = fmaxf(mx, __shfl_xor(mx, o));
  __shared__ float red[4], red2[4];
  int w = t >> 6;
  if ((t & 63) == 0) red[w] = mx;
  __syncthreads();
  mx = fmaxf(fmaxf(red[0], red[1]), fmaxf(red[2], red[3]));
  float e0 = __expf(x.x - mx), e1 = __expf(x.y - mx);
  float e2 = __expf(x.z - mx), e3 = __expf(x.w - mx);
  float s = e0 + e1 + e2 + e3;
  #pragma unroll
  for (int o = 32; o; o >>= 1) s += __shfl_xor(s, o);
  if ((t & 63) == 0) red2[w] = s;
  __syncthreads();
  s = red2[0] + red2[1] + red2[2] + red2[3];
  float inv = 1.f / s;
  ushort4 H, L;
  split2(e0 * inv, H.x, L.x); split2(e1 * inv, H.y, L.y);
  split2(e2 * inv, H.z, L.z); split2(e3 * inv, H.w, L.w);
  long o = row * 1024 + (long)t * 4;
  *(ushort4*)(Ph + o)  = H;
  *(ushort4*)(Plo + o) = L;
}

// -------- softmax over Nl (cols), writes P2t[b][v][128] (k>=77 zero) --------
__global__ __launch_bounds__(128) void softmax_cols(const float* __restrict__ a,
                                                    unsigned short* __restrict__ Ph,
                                                    unsigned short* __restrict__ Plo) {
  __shared__ float tile[77 * 129];
  __shared__ float inv[128];
  int t = threadIdx.x;                  // 0..127
  int c = blockIdx.x;                   // v-chunk (of 128)
  int b = blockIdx.y;
  const float* src = a + (long)b * 77 * 1024 + c * 128;
  for (int r = 0; r < 77; ++r) tile[r * 129 + t] = src[(long)r * 1024 + t];
  __syncthreads();
  float mx = -1e30f;
  for (int r = 0; r < 77; ++r) mx = fmaxf(mx, tile[r * 129 + t]);
  float s = 0.f;
  for (int r = 0; r < 77; ++r) {
    float e = __expf(tile[r * 129 + t] - mx);
    tile[r * 129 + t] = e;
    s += e;
  }
  inv[t] = 1.f / s;
  __syncthreads();
  unsigned short* dh = Ph  + ((long)b * 1024 + c * 128) * 128;
  unsigned short* dl = Plo + ((long)b * 1024 + c * 128) * 128;
  for (int vb = 0; vb < 128; vb += 2) {
    int v = vb + (t >> 6);
    int k = (t & 63) * 2;
    float iv = inv[v];
    float p0 = (k     < 77) ? tile[k * 129 + v] * iv       : 0.f;
    float p1 = (k + 1 < 77) ? tile[(k + 1) * 129 + v] * iv : 0.f;
    ushort2 H, L;
    split2(p0, H.x, L.x); split2(p1, H.y, L.y);
    *(ushort2*)(dh + (long)v * 128 + k) = H;
    *(ushort2*)(dl + (long)v * 128 + k) = L;
  }
}

// ---------------------------------------------------------------------------
extern "C" void kernel_launch(void* const* d_in, const int* in_sizes, int n_in,
                              void* d_out, int out_size, void* d_ws, size_t ws_size,
                              hipStream_t stream) {
  const float* fv   = (const float*)d_in[0];
  const float* fl   = (const float*)d_in[1];
  const float* W_vk = (const float*)d_in[2];
  const float* b_vk = (const float*)d_in[3];
  const float* W_vv = (const float*)d_in[4];
  const float* b_vv = (const float*)d_in[5];
  const float* W_lk = (const float*)d_in[6];
  const float* b_lk = (const float*)d_in[7];
  const float* W_lv = (const float*)d_in[8];
  const float* b_lv = (const float*)d_in[9];
  const float* W_m  = (const float*)d_in[10];
  const float* b_m  = (const float*)d_in[11];

  char* base = (char*)d_ws;
  size_t off = 0;
  auto take = [&](size_t bytes) -> char* {
    char* p = base + off;
    off = (off + bytes + 255) & ~(size_t)255;
    return p;
  };

  // weights (concatenated, pre-transposed, bf16 pairs)
  unsigned short* wcatv_h = (unsigned short*)take(1572864);  // [1024][768]
  unsigned short* wcatv_l = (unsigned short*)take(1572864);
  unsigned short* wcatl_h = (unsigned short*)take(1048576);  // [1024][512]
  unsigned short* wcatl_l = (unsigned short*)take(1048576);
  unsigned short* wm_h    = (unsigned short*)take(196608);   // [768][128]
  unsigned short* wm_l    = (unsigned short*)take(196608);
  // intermediates
  unsigned short* fkl_h  = (unsigned short*)take(2523136);   // [2464][512]
  unsigned short* fkl_l  = (unsigned short*)take(2523136);
  unsigned short* fvl_h  = (unsigned short*)take(2523136);   // [2464][512]
  unsigned short* fvl_l  = (unsigned short*)take(2523136);
  unsigned short* fkv_h  = (unsigned short*)take(33554432);  // [32768][512]
  unsigned short* fkv_l  = (unsigned short*)take(33554432);
  unsigned short* fvvT_h = (unsigned short*)take(33554432);  // [32][512][1024]
  unsigned short* fvvT_l = (unsigned short*)take(33554432);
  float*          araw   = (float*)take(10092544);           // [32][77][1024]
  unsigned short* p1_h   = (unsigned short*)take(5046272);   // [2464][1024]
  unsigned short* p1_l   = (unsigned short*)take(5046272);
  unsigned short* p2t_h  = (unsigned short*)take(8388608);   // [32][1024][128]
  unsigned short* p2t_l  = (unsigned short*)take(8388608);
  unsigned short* fav_h  = (unsigned short*)take(4194304);   // [32][128][512]
  unsigned short* fav_l  = (unsigned short*)take(4194304);
  unsigned short* s_h    = (unsigned short*)take(1048576);   // [32][128][128]
  unsigned short* s_l    = (unsigned short*)take(1048576);
  unsigned short* tt_h   = (unsigned short*)take(6291456);   // [32][768][128]
  unsigned short* tt_l   = (unsigned short*)take(6291456);

  if (off > ws_size) return;  // workspace too small: fail loudly via mismatch

  // ---- prep weights ----
  prep_weight<<<dim3(16, 24), 256, 0, stream>>>(W_vk, wcatv_h, wcatv_l, 768, 512, 768);
  prep_weight<<<dim3(16, 24), 256, 0, stream>>>(W_vv, wcatv_h + 512 * 768, wcatv_l + 512 * 768, 768, 512, 768);
  prep_weight<<<dim3(16, 16), 256, 0, stream>>>(W_lk, wcatl_h, wcatl_l, 512, 512, 512);
  prep_weight<<<dim3(16, 16), 256, 0, stream>>>(W_lv, wcatl_h + 512 * 512, wcatl_l + 512 * 512, 512, 512, 512);
  prep_weight<<<dim3(24, 4), 256, 0, stream>>>(W_m, wm_h, wm_l, 77, 768, 128);

  // ---- K1f: [fk_l | fv_l] = fl @ [W_lk | W_lv] + bias  (M=2464, N=1024, K=512)
  {
    GemmArgs g{}; g.Af = fl; g.Bh = wcatl_h; g.Blo = wcatl_l;
    g.K = 512; g.Mld = 2464; g.Nld = 1024; g.lda = 512; g.ldb = 512; g.sA = 0; g.sB = 0;
    EpiDualL e{fkl_h, fkl_l, fvl_h, fvl_l, b_lk, b_lv};
    gemm3<true, false, 4, EpiDualL><<<dim3(8, 20, 1), 256, 0, stream>>>(g, e);
  }
  // ---- K2f: [fk_v | fv_v^T] = fv @ [W_vk | W_vv] + bias (M=32768, N=1024, K=768)
  {
    GemmArgs g{}; g.Af = fv; g.Bh = wcatv_h; g.Blo = wcatv_l;
    g.K = 768; g.Mld = 32768; g.Nld = 1024; g.lda = 768; g.ldb = 768; g.sA = 0; g.sB = 0;
    EpiDualV e{fkv_h, fkv_l, fvvT_h, fvvT_l, b_vk, b_vv};
    gemm3<true, true, 4, EpiDualV><<<dim3(8, 256, 1), 256, 0, stream>>>(g, e);
  }
  // ---- K3: a_raw[b][l][v] = fk_l . fk_v / sqrt(512)  (BN=64 -> 512 blocks)
  {
    GemmArgs g{}; g.Ah = fkl_h; g.Alo = fkl_l; g.Bh = fkv_h; g.Blo = fkv_l;
    g.K = 512; g.Mld = 77; g.Nld = 1024; g.lda = 512; g.ldb = 512;
    g.sA = 77 * 512; g.sB = 1024 * 512;
    EpiScore e{araw};
    gemm3<false, false, 2, EpiScore><<<dim3(16, 1, 32), 256, 0, stream>>>(g, e);
  }
  // ---- softmaxes ----
  softmax_rows<<<2464, 256, 0, stream>>>(araw, p1_h, p1_l);
  softmax_cols<<<dim3(8, 32), 128, 0, stream>>>(araw, p2t_h, p2t_l);
  // ---- K5: fa_v[b][l][e] = P1 @ fv_v (via fv_vT)  (BN=64 -> 256 blocks)
  {
    GemmArgs g{}; g.Ah = p1_h; g.Alo = p1_l; g.Bh = fvvT_h; g.Blo = fvvT_l;
    g.K = 1024; g.Mld = 77; g.Nld = 512; g.lda = 1024; g.ldb = 1024;
    g.sA = 77 * 1024; g.sB = 512 * 1024;
    EpiBF16Pair e{fav_h, fav_l, nullptr, 128 * 512, 512, 128};
    gemm3<false, false, 2, EpiBF16Pair><<<dim3(8, 1, 32), 256, 0, stream>>>(g, e);
  }
  // ---- S[b][l'][l] = fv_l . fa_v  (BN=64 -> 64 blocks)
  {
    GemmArgs g{}; g.Ah = fvl_h; g.Alo = fvl_l; g.Bh = fav_h; g.Blo = fav_l;
    g.K = 512; g.Mld = 77; g.Nld = 128; g.lda = 512; g.ldb = 512;
    g.sA = 77 * 512; g.sB = 128 * 512;
    EpiBF16Pair e{s_h, s_l, nullptr, 128 * 128, 128, 128};
    gemm3<false, false, 2, EpiBF16Pair><<<dim3(2, 1, 32), 256, 0, stream>>>(g, e);
  }
  // ---- T_t[b][o][l'] = (S @ W_m)^T  (BN=64 -> 384 blocks; zero l'>=77)
  {
    GemmArgs g{}; g.Ah = s_h; g.Alo = s_l; g.Bh = wm_h; g.Blo = wm_l;
    g.K = 128; g.Mld = 128; g.Nld = 768; g.lda = 128; g.ldb = 128;
    g.sA = 128 * 128; g.sB = 0;
    EpiTransT e{tt_h, tt_l};
    gemm3<false, false, 2, EpiTransT><<<dim3(12, 1, 32), 256, 0, stream>>>(g, e);
  }
  // ---- OUT: out[b][v][o] = P2t @ T_t + b_m  (M=1024, N=768, K=128)
  {
    GemmArgs g{}; g.Ah = p2t_h; g.Alo = p2t_l; g.Bh = tt_h; g.Blo = tt_l;
    g.K = 128; g.Mld = 1024; g.Nld = 768; g.lda = 128; g.ldb = 128;
    g.sA = 1024 * 128; g.sB = 768 * 128;
    EpiOutB e{(float*)d_out, b_m};
    gemm3<false, false, 4, EpiOutB><<<dim3(6, 8, 32), 256, 0, stream>>>(g, e);
  }
  (void)in_sizes; (void)n_in; (void)out_size;
}

// Round 7
// 548.147 us; speedup vs baseline: 1.1864x; 1.1864x over previous
//
#include <hip/hip_runtime.h>

// ---------------------------------------------------------------------------
// DenseLanguageGuidanceModule on MI355X (gfx950)
// bf16 hi/lo split GEMMs (x3 MFMA, fp32 accumulate) for ~fp32 accuracy.
// Round 7: revert to round-5 dbuf pipeline (233us K2f); add MI/NJ-templated
// 64x64 tile (32KB LDS, 5 blocks/CU) for small GEMMs; fuse weight-prep.
// ---------------------------------------------------------------------------

using s16x8  = __attribute__((ext_vector_type(8))) short;
using f32x4v = __attribute__((ext_vector_type(4))) float;

__device__ __forceinline__ unsigned short f2bf(float f) {
  unsigned int u = __float_as_uint(f);
  u += 0x7fffu + ((u >> 16) & 1u);     // RNE
  return (unsigned short)(u >> 16);
}
__device__ __forceinline__ float bf2f(unsigned short h) {
  return __uint_as_float(((unsigned int)h) << 16);
}
__device__ __forceinline__ void split2(float v, unsigned short &hh, unsigned short &ll) {
  hh = f2bf(v);
  ll = f2bf(v - bf2f(hh));
}
__device__ __forceinline__ void split8v(float4 a, float4 b, s16x8& H, s16x8& L) {
  unsigned short hh, ll;
  split2(a.x, hh, ll); H[0] = (short)hh; L[0] = (short)ll;
  split2(a.y, hh, ll); H[1] = (short)hh; L[1] = (short)ll;
  split2(a.z, hh, ll); H[2] = (short)hh; L[2] = (short)ll;
  split2(a.w, hh, ll); H[3] = (short)hh; L[3] = (short)ll;
  split2(b.x, hh, ll); H[4] = (short)hh; L[4] = (short)ll;
  split2(b.y, hh, ll); H[5] = (short)hh; L[5] = (short)ll;
  split2(b.z, hh, ll); H[6] = (short)hh; L[6] = (short)ll;
  split2(b.w, hh, ll); H[7] = (short)hh; L[7] = (short)ll;
}

// async global->LDS, 16B per lane; LDS dest is wave-uniform base + lane*16
__device__ __forceinline__ void gload16(const unsigned short* g, unsigned short* l) {
  __builtin_amdgcn_global_load_lds(
      (const __attribute__((address_space(1))) unsigned int*)(const void*)g,
      (__attribute__((address_space(3))) unsigned int*)(void*)l,
      16, 0, 0);
}

// ---- fused weight prep: transpose W[K][N] -> Wt[N][Kpad] bf16 pair --------
struct PrepSeg { const float* W; unsigned short* Wh; unsigned short* Wl;
                 int K, N, Kpad, ntx, tOff; };
struct PrepArgs { PrepSeg s[5]; };

__global__ __launch_bounds__(256) void prep_all(PrepArgs pa) {
  __shared__ float tile[32][33];
  int bid = blockIdx.x;
  int si = 0;
  #pragma unroll
  for (int i = 1; i < 5; ++i) if (bid >= pa.s[i].tOff) si = i;
  PrepSeg sg = pa.s[si];
  int local = bid - sg.tOff;
  int nb = (local % sg.ntx) * 32, kb = (local / sg.ntx) * 32;
  int tx = threadIdx.x & 31, ty = threadIdx.x >> 5;   // 32 x 8
  #pragma unroll
  for (int i = 0; i < 32; i += 8) {
    int k = kb + ty + i, n = nb + tx;
    tile[ty + i][tx] = (k < sg.K && n < sg.N) ? sg.W[(long)k * sg.N + n] : 0.f;
  }
  __syncthreads();
  #pragma unroll
  for (int i = 0; i < 32; i += 8) {
    int n = nb + ty + i, k = kb + tx;
    if (n < sg.N && k < sg.Kpad) {
      unsigned short hh, ll;
      split2(tile[tx][ty + i], hh, ll);
      sg.Wh[(long)n * sg.Kpad + k] = hh;
      sg.Wl[(long)n * sg.Kpad + k] = ll;
    }
  }
}

// ---------------- generic NT GEMM, bf16 hi/lo x3, 2-phase dbuf ----------------
// C[m][n] = sum_k A[m][k] * Bt[n][k]
// Tile (MI*32) x (NJ*32), BK=32, 256 threads (4 waves 2x2).
// A: raw fp32 (AF32, MI==4 only: reg prefetch + in-reg split + swizzled
//    ds_write) or pre-split bf16 pair (DMA, source-XOR swizzle).
// B: pre-split pair, DMA. LDS dbuf: MI4/NJ4=64KB (2 blk/CU), MI2/NJ2=32KB (5).
struct GemmArgs {
  const unsigned short *Ah, *Alo, *Bh, *Blo;
  const float *Af;  // fp32 A source (when AF32)
  int K;            // multiple of 32
  int Mld, Nld;     // row clamp bounds
  int lda, ldb;     // row strides (elements)
  long long sA, sB; // batch strides (elements)
};

template <bool AF32, bool SWZ, int MI, int NJ, class Epi>
__global__ __launch_bounds__(256, 2) void gemmP(GemmArgs g, Epi epi) {
  static_assert(!AF32 || MI == 4, "AF32 path assumes MI==4");
  constexpr int ASZ = MI * 1024;       // shorts per A component per buffer
  constexpr int BSZ = NJ * 1024;
  constexpr int BUF = 2 * ASZ + 2 * BSZ;
  __shared__ __align__(16) unsigned short sm[2 * BUF];

  int bidx = blockIdx.x, bidy = blockIdx.y;
  if constexpr (SWZ) {   // XCD-contiguous remap (requires nwg % 8 == 0)
    int nx = gridDim.x;
    int nwg = nx * gridDim.y;
    int orig = bidx + bidy * nx;
    int swz = (orig & 7) * (nwg >> 3) + (orig >> 3);
    bidx = swz % nx; bidy = swz / nx;
  }

  const int t    = threadIdx.x;
  const int b    = blockIdx.z;
  const int m0   = bidy * (MI * 32);
  const int n0   = bidx * (NJ * 32);
  const int lane = t & 63;
  const int w    = t >> 6;
  const int wr   = (w >> 1) * (MI * 16);
  const int wc   = (w & 1) * (NJ * 16);

  const long long aBase = (long long)b * g.sA;
  const long long bBase = (long long)b * g.sB;

  // ---- DMA staging coords ----
  const int clk = lane & 3;
  const int rwB = (NJ == 4) ? ((w << 5) + (lane >> 2)) : ((w << 4) + (lane >> 2));
  const int sckB = ((clk ^ ((rwB >> 1) & 3)) << 3);
  int br0 = n0 + rwB;      if (br0 > g.Nld - 1) br0 = g.Nld - 1;
  int br1 = n0 + rwB + 16; if (br1 > g.Nld - 1) br1 = g.Nld - 1;
  const long long bR0d = bBase + (long long)br0 * g.ldb + sckB;
  const long long bR1d = bBase + (long long)br1 * g.ldb + sckB;
  const int dB0 = w * ((NJ == 4) ? 1024 : 512);
  const int dB1 = dB0 + 512;                           // NJ==4 only
  const int rwA = (MI == 4) ? ((w << 5) + (lane >> 2)) : ((w << 4) + (lane >> 2));
  const int sckA = ((clk ^ ((rwA >> 1) & 3)) << 3);
  int arD0 = m0 + rwA;      if (arD0 > g.Mld - 1) arD0 = g.Mld - 1;
  int arD1 = m0 + rwA + 16; if (arD1 > g.Mld - 1) arD1 = g.Mld - 1;
  const long long aR0d = aBase + (long long)arD0 * g.lda + sckA;
  const long long aR1d = aBase + (long long)arD1 * g.lda + sckA;
  const int dA0 = w * ((MI == 4) ? 1024 : 512);
  const int dA1 = dA0 + 512;                           // MI==4 only

  // ---- AF32 reg-staging coords (MI==4; swizzled ds_write) ----
  const int rA0 = t >> 2, rA1 = 64 + (t >> 2), cc = t & 3;
  const int cOff = cc << 3;
  int mr0 = m0 + rA0; if (mr0 > g.Mld - 1) mr0 = g.Mld - 1;
  int mr1 = m0 + rA1; if (mr1 > g.Mld - 1) mr1 = g.Mld - 1;
  const long long aR0 = aBase + (long long)mr0 * g.lda;
  const long long aR1 = aBase + (long long)mr1 * g.lda;
  const int wA0 = rA0 * 32 + ((cc ^ ((rA0 >> 1) & 3)) << 3);
  const int wA1 = rA1 * 32 + ((cc ^ ((rA1 >> 1) & 3)) << 3);

  // read-fragment offsets (constant; add buf base)
  int roffA[MI], roffB[NJ];
  #pragma unroll
  for (int i = 0; i < MI; ++i) {
    int row = wr + i * 16 + (lane & 15);
    int ch  = lane >> 4;
    roffA[i] = row * 32 + ((ch ^ ((row >> 1) & 3)) << 3);
  }
  #pragma unroll
  for (int j = 0; j < NJ; ++j) {
    int row = wc + j * 16 + (lane & 15);
    int ch  = lane >> 4;
    roffB[j] = row * 32 + ((ch ^ ((row >> 1) & 3)) << 3);
  }

  f32x4v acc[MI][NJ];
  #pragma unroll
  for (int i = 0; i < MI; ++i)
    #pragma unroll
    for (int j = 0; j < NJ; ++j)
      #pragma unroll
      for (int r = 0; r < 4; ++r) acc[i][j][r] = 0.f;

  float4 pa0, pa1, pa2, pa3;   // AF32 prefetch regs

  auto issueDMA = [&](int k0, int p) {
    unsigned short* bb = sm + p * BUF;
    gload16(g.Bh  + (bR0d + k0), bb + 2 * ASZ + dB0);
    gload16(g.Blo + (bR0d + k0), bb + 2 * ASZ + BSZ + dB0);
    if constexpr (NJ == 4) {
      gload16(g.Bh  + (bR1d + k0), bb + 2 * ASZ + dB1);
      gload16(g.Blo + (bR1d + k0), bb + 2 * ASZ + BSZ + dB1);
    }
    if constexpr (!AF32) {
      gload16(g.Ah  + (aR0d + k0), bb + dA0);
      gload16(g.Alo + (aR0d + k0), bb + ASZ + dA0);
      if constexpr (MI == 4) {
        gload16(g.Ah  + (aR1d + k0), bb + dA1);
        gload16(g.Alo + (aR1d + k0), bb + ASZ + dA1);
      }
    }
  };
  auto issueA = [&](int k0) {
    if constexpr (AF32) {
      const float* s0 = g.Af + (aR0 + k0 + cOff);
      const float* s1 = g.Af + (aR1 + k0 + cOff);
      pa0 = *(const float4*)s0; pa1 = *(const float4*)(s0 + 4);
      pa2 = *(const float4*)s1; pa3 = *(const float4*)(s1 + 4);
    }
  };
  auto writeA = [&](int p) {
    if constexpr (AF32) {
      unsigned short* base = sm + p * BUF;
      s16x8 H, L;
      split8v(pa0, pa1, H, L);
      *(s16x8*)(base + wA0) = H; *(s16x8*)(base + ASZ + wA0) = L;
      split8v(pa2, pa3, H, L);
      *(s16x8*)(base + wA1) = H; *(s16x8*)(base + ASZ + wA1) = L;
    }
  };

  // prologue: stage tile 0 into buf 0
  issueDMA(0, 0);
  if constexpr (AF32) { issueA(0); writeA(0); }
  int p = 0;
  const int nkt = g.K >> 5;
  for (int kt = 0; kt < nkt; ++kt) {
    asm volatile("s_waitcnt vmcnt(0)" ::: "memory");  // tile-kt DMA landed
    __syncthreads();                                  // + all waves' A-writes visible
    if (kt + 1 < nkt) {
      issueDMA((kt + 1) << 5, p ^ 1);                 // flies under compute
      issueA((kt + 1) << 5);
    }
    unsigned short* base = sm + p * BUF;
    s16x8 ah[MI], al[MI], bh[NJ], bl[NJ];
    #pragma unroll
    for (int i = 0; i < MI; ++i) {
      ah[i] = *(const s16x8*)(base + roffA[i]);
      al[i] = *(const s16x8*)(base + ASZ + roffA[i]);
    }
    #pragma unroll
    for (int j = 0; j < NJ; ++j) {
      bh[j] = *(const s16x8*)(base + 2 * ASZ + roffB[j]);
      bl[j] = *(const s16x8*)(base + 2 * ASZ + BSZ + roffB[j]);
    }
    #pragma unroll
    for (int i = 0; i < MI; ++i)
      #pragma unroll
      for (int j = 0; j < NJ; ++j) {
        acc[i][j] = __builtin_amdgcn_mfma_f32_16x16x32_bf16(ah[i], bh[j], acc[i][j], 0, 0, 0);
        acc[i][j] = __builtin_amdgcn_mfma_f32_16x16x32_bf16(ah[i], bl[j], acc[i][j], 0, 0, 0);
        acc[i][j] = __builtin_amdgcn_mfma_f32_16x16x32_bf16(al[i], bh[j], acc[i][j], 0, 0, 0);
      }
    if (kt + 1 < nkt) writeA(p ^ 1);   // regs arrived during compute
    p ^= 1;
  }
  // epilogue: D row=(lane>>4)*4+r, col=lane&15
  #pragma unroll
  for (int i = 0; i < MI; ++i)
    #pragma unroll
    for (int j = 0; j < NJ; ++j) {
      int mm = m0 + wr + i * 16 + ((lane >> 4) << 2);
      int nn = n0 + wc + j * 16 + (lane & 15);
      epi(b, mm, nn, acc[i][j]);
    }
}

// ---------------- epilogues ----------------
struct EpiBF16Pair {   // out[b][m][n] bf16 hi/lo pair (+optional bias)
  unsigned short *h, *lo; const float* bias; long long bs; int ld; int Mst;
  __device__ void operator()(int b, int m, int n, f32x4v v) const {
    float bb = bias ? bias[n] : 0.f;
    #pragma unroll
    for (int r = 0; r < 4; ++r) {
      int mm = m + r;
      if (mm < Mst) {
        long long o = (long long)b * bs + (long long)mm * ld + n;
        unsigned short hh, ll;
        split2(v[r] + bb, hh, ll);
        h[o] = hh; lo[o] = ll;
      }
    }
  }
};

struct EpiDualL {      // K1f: n<512 -> fkl[m][n]; n>=512 -> fvl[m][n-512]
  unsigned short *kh, *kl, *vh, *vl; const float *bk, *bv;
  __device__ void operator()(int, int m, int n, f32x4v v) const {
    bool lo512 = n < 512;
    float bb = lo512 ? bk[n] : bv[n - 512];
    int nn = lo512 ? n : n - 512;
    unsigned short* H = lo512 ? kh : vh;
    unsigned short* L = lo512 ? kl : vl;
    #pragma unroll
    for (int r = 0; r < 4; ++r) {
      int mm = m + r;
      if (mm < 2464) {
        long long o = (long long)mm * 512 + nn;
        unsigned short hh, ll;
        split2(v[r] + bb, hh, ll);
        H[o] = hh; L[o] = ll;
      }
    }
  }
};

struct EpiDualV {      // K2f: n<512 -> fkv[m][n]; n>=512 -> fvvT[b2][n-512][v]
  unsigned short *kh, *kl, *vh, *vl; const float *bk, *bv;
  __device__ void operator()(int, int m, int n, f32x4v v) const {
    if (n < 512) {
      float bb = bk[n];
      #pragma unroll
      for (int r = 0; r < 4; ++r) {
        long long o = (long long)(m + r) * 512 + n;
        unsigned short hh, ll;
        split2(v[r] + bb, hh, ll);
        kh[o] = hh; kl[o] = ll;
      }
    } else {
      int b2 = m >> 10, vv = m & 1023;
      float bb = bv[n - 512];
      ushort4 H, L;
      split2(v[0] + bb, H.x, L.x); split2(v[1] + bb, H.y, L.y);
      split2(v[2] + bb, H.z, L.z); split2(v[3] + bb, H.w, L.w);
      long long o = ((long long)b2 * 512 + (n - 512)) * 1024 + vv;
      *(ushort4*)(vh + o) = H;
      *(ushort4*)(vl + o) = L;
    }
  }
};

struct EpiScore {      // K3: a_raw[b][m][n] fp32, scaled, m<77
  float* out;
  __device__ void operator()(int b, int m, int n, f32x4v v) const {
    #pragma unroll
    for (int r = 0; r < 4; ++r) {
      int mm = m + r;
      if (mm < 77)
        out[((long long)b * 77 + mm) * 1024 + n] = v[r] * 0.04419417382415922f;
    }
  }
};

struct EpiTransT {     // T-gemm: T_t[b][o=n][l=m+r], zero l>=77
  unsigned short *h, *lo;
  __device__ void operator()(int b, int m, int n, f32x4v v) const {
    #pragma unroll
    for (int r = 0; r < 4; ++r) {
      int mm = m + r;
      float val = (mm < 77) ? v[r] : 0.f;
      long long o = (long long)b * 98304 + (long long)n * 128 + mm;
      unsigned short hh, ll;
      split2(val, hh, ll);
      h[o] = hh; lo[o] = ll;
    }
  }
};

struct EpiOutB {       // OUT: d_out[b*1024+m][768] fp32 + b_m
  float* out; const float* bias;
  __device__ void operator()(int b, int m, int n, f32x4v v) const {
    float bb = bias[n];
    #pragma unroll
    for (int r = 0; r < 4; ++r)
      out[(long long)(b * 1024 + m + r) * 768 + n] = v[r] + bb;
  }
};

// ---------------- softmax over Nv (rows of a_raw) ----------------
__global__ __launch_bounds__(256) void softmax_rows(const float* __restrict__ a,
                                                    unsigned short* __restrict__ Ph,
                                                    unsigned short* __restrict__ Plo) {
  long row = blockIdx.x;                 // (b*77+l)
  const float* src = a + row * 1024;
  int t = threadIdx.x;
  float4 x = ((const float4*)src)[t];
  float mx = fmaxf(fmaxf(x.x, x.y), fmaxf(x.z, x.w));
  #pragma unroll
  for (int o = 32; o; o >>= 1) mx = fmaxf(mx, __shfl_xor(mx, o));
  __shared__ float red[4], red2[4];
  int w = t >> 6;
  if ((t & 63) == 0) red[w] = mx;
  __syncthreads();
  mx = fmaxf(fmaxf(red[0], red[1]), fmaxf(red[2], red[3]));
  float e0 = __expf(x.x - mx), e1 = __expf(x.y - mx);
  float e2 = __expf(x.z - mx), e3 = __expf(x.w - mx);
  float s = e0 + e1 + e2 + e3;
  #pragma unroll
  for (int o = 32; o; o >>= 1) s += __shfl_xor(s, o);
  if ((t & 63) == 0) red2[w] = s;
  __syncthreads();
  s = red2[0] + red2[1] + red2[2] + red2[3];
  float inv = 1.f / s;
  ushort4 H, L;
  split2(e0 * inv, H.x, L.x); split2(e1 * inv, H.y, L.y);
  split2(e2 * inv, H.z, L.z); split2(e3 * inv, H.w, L.w);
  long o = row * 1024 + (long)t * 4;
  *(ushort4*)(Ph + o)  = H;
  *(ushort4*)(Plo + o) = L;
}

// -------- softmax over Nl (cols), writes P2t[b][v][128] (k>=77 zero) --------
__global__ __launch_bounds__(128) void softmax_cols(const float* __restrict__ a,
                                                    unsigned short* __restrict__ Ph,
                                                    unsigned short* __restrict__ Plo) {
  __shared__ float tile[77 * 129];
  __shared__ float inv[128];
  int t = threadIdx.x;                  // 0..127
  int c = blockIdx.x;                   // v-chunk (of 128)
  int b = blockIdx.y;
  const float* src = a + (long)b * 77 * 1024 + c * 128;
  for (int r = 0; r < 77; ++r) tile[r * 129 + t] = src[(long)r * 1024 + t];
  __syncthreads();
  float mx = -1e30f;
  for (int r = 0; r < 77; ++r) mx = fmaxf(mx, tile[r * 129 + t]);
  float s = 0.f;
  for (int r = 0; r < 77; ++r) {
    float e = __expf(tile[r * 129 + t] - mx);
    tile[r * 129 + t] = e;
    s += e;
  }
  inv[t] = 1.f / s;
  __syncthreads();
  unsigned short* dh = Ph  + ((long)b * 1024 + c * 128) * 128;
  unsigned short* dl = Plo + ((long)b * 1024 + c * 128) * 128;
  for (int vb = 0; vb < 128; vb += 2) {
    int v = vb + (t >> 6);
    int k = (t & 63) * 2;
    float iv = inv[v];
    float p0 = (k     < 77) ? tile[k * 129 + v] * iv       : 0.f;
    float p1 = (k + 1 < 77) ? tile[(k + 1) * 129 + v] * iv : 0.f;
    ushort2 H, L;
    split2(p0, H.x, L.x); split2(p1, H.y, L.y);
    *(ushort2*)(dh + (long)v * 128 + k) = H;
    *(ushort2*)(dl + (long)v * 128 + k) = L;
  }
}

// ---------------------------------------------------------------------------
extern "C" void kernel_launch(void* const* d_in, const int* in_sizes, int n_in,
                              void* d_out, int out_size, void* d_ws, size_t ws_size,
                              hipStream_t stream) {
  const float* fv   = (const float*)d_in[0];
  const float* fl   = (const float*)d_in[1];
  const float* W_vk = (const float*)d_in[2];
  const float* b_vk = (const float*)d_in[3];
  const float* W_vv = (const float*)d_in[4];
  const float* b_vv = (const float*)d_in[5];
  const float* W_lk = (const float*)d_in[6];
  const float* b_lk = (const float*)d_in[7];
  const float* W_lv = (const float*)d_in[8];
  const float* b_lv = (const float*)d_in[9];
  const float* W_m  = (const float*)d_in[10];
  const float* b_m  = (const float*)d_in[11];

  char* base = (char*)d_ws;
  size_t off = 0;
  auto take = [&](size_t bytes) -> char* {
    char* p = base + off;
    off = (off + bytes + 255) & ~(size_t)255;
    return p;
  };

  // weights (concatenated, pre-transposed, bf16 pairs)
  unsigned short* wcatv_h = (unsigned short*)take(1572864);  // [1024][768]
  unsigned short* wcatv_l = (unsigned short*)take(1572864);
  unsigned short* wcatl_h = (unsigned short*)take(1048576);  // [1024][512]
  unsigned short* wcatl_l = (unsigned short*)take(1048576);
  unsigned short* wm_h    = (unsigned short*)take(196608);   // [768][128]
  unsigned short* wm_l    = (unsigned short*)take(196608);
  // intermediates
  unsigned short* fkl_h  = (unsigned short*)take(2523136);   // [2464][512]
  unsigned short* fkl_l  = (unsigned short*)take(2523136);
  unsigned short* fvl_h  = (unsigned short*)take(2523136);   // [2464][512]
  unsigned short* fvl_l  = (unsigned short*)take(2523136);
  unsigned short* fkv_h  = (unsigned short*)take(33554432);  // [32768][512]
  unsigned short* fkv_l  = (unsigned short*)take(33554432);
  unsigned short* fvvT_h = (unsigned short*)take(33554432);  // [32][512][1024]
  unsigned short* fvvT_l = (unsigned short*)take(33554432);
  float*          araw   = (float*)take(10092544);           // [32][77][1024]
  unsigned short* p1_h   = (unsigned short*)take(5046272);   // [2464][1024]
  unsigned short* p1_l   = (unsigned short*)take(5046272);
  unsigned short* p2t_h  = (unsigned short*)take(8388608);   // [32][1024][128]
  unsigned short* p2t_l  = (unsigned short*)take(8388608);
  unsigned short* fav_h  = (unsigned short*)take(4194304);   // [32][128][512]
  unsigned short* fav_l  = (unsigned short*)take(4194304);
  unsigned short* s_h    = (unsigned short*)take(1048576);   // [32][128][128]
  unsigned short* s_l    = (unsigned short*)take(1048576);
  unsigned short* tt_h   = (unsigned short*)take(6291456);   // [32][768][128]
  unsigned short* tt_l   = (unsigned short*)take(6291456);

  if (off > ws_size) return;  // workspace too small: fail loudly via mismatch

  // ---- prep weights (one fused launch, 1376 tiles) ----
  {
    PrepArgs pa;
    pa.s[0] = {W_vk, wcatv_h,               wcatv_l,               768, 512, 768, 16, 0};
    pa.s[1] = {W_vv, wcatv_h + 512 * 768,   wcatv_l + 512 * 768,   768, 512, 768, 16, 384};
    pa.s[2] = {W_lk, wcatl_h,               wcatl_l,               512, 512, 512, 16, 768};
    pa.s[3] = {W_lv, wcatl_h + 512 * 512,   wcatl_l + 512 * 512,   512, 512, 512, 16, 1024};
    pa.s[4] = {W_m,  wm_h,                  wm_l,                   77, 768, 128, 24, 1280};
    prep_all<<<1376, 256, 0, stream>>>(pa);
  }

  // ---- K1f: [fk_l | fv_l] = fl @ [W_lk | W_lv] + bias  (M=2464, N=1024, K=512)
  {
    GemmArgs g{}; g.Af = fl; g.Bh = wcatl_h; g.Blo = wcatl_l;
    g.K = 512; g.Mld = 2464; g.Nld = 1024; g.lda = 512; g.ldb = 512; g.sA = 0; g.sB = 0;
    EpiDualL e{fkl_h, fkl_l, fvl_h, fvl_l, b_lk, b_lv};
    gemmP<true, false, 4, 4, EpiDualL><<<dim3(8, 20, 1), 256, 0, stream>>>(g, e);
  }
  // ---- K2f: [fk_v | fv_v^T] = fv @ [W_vk | W_vv] + bias (M=32768, N=1024, K=768)
  {
    GemmArgs g{}; g.Af = fv; g.Bh = wcatv_h; g.Blo = wcatv_l;
    g.K = 768; g.Mld = 32768; g.Nld = 1024; g.lda = 768; g.ldb = 768; g.sA = 0; g.sB = 0;
    EpiDualV e{fkv_h, fkv_l, fvvT_h, fvvT_l, b_vk, b_vv};
    gemmP<true, true, 4, 4, EpiDualV><<<dim3(8, 256, 1), 256, 0, stream>>>(g, e);
  }
  // ---- K3: a_raw[b][l][v] = fk_l . fk_v / sqrt(512)  (64x64 tile, 1024 blocks)
  {
    GemmArgs g{}; g.Ah = fkl_h; g.Alo = fkl_l; g.Bh = fkv_h; g.Blo = fkv_l;
    g.K = 512; g.Mld = 77; g.Nld = 1024; g.lda = 512; g.ldb = 512;
    g.sA = 77 * 512; g.sB = 1024 * 512;
    EpiScore e{araw};
    gemmP<false, false, 2, 2, EpiScore><<<dim3(16, 2, 32), 256, 0, stream>>>(g, e);
  }
  // ---- softmaxes ----
  softmax_rows<<<2464, 256, 0, stream>>>(araw, p1_h, p1_l);
  softmax_cols<<<dim3(8, 32), 128, 0, stream>>>(araw, p2t_h, p2t_l);
  // ---- K5: fa_v[b][l][e] = P1 @ fv_v (via fv_vT)  (64x64 tile, 512 blocks)
  {
    GemmArgs g{}; g.Ah = p1_h; g.Alo = p1_l; g.Bh = fvvT_h; g.Blo = fvvT_l;
    g.K = 1024; g.Mld = 77; g.Nld = 512; g.lda = 1024; g.ldb = 1024;
    g.sA = 77 * 1024; g.sB = 512 * 1024;
    EpiBF16Pair e{fav_h, fav_l, nullptr, 128 * 512, 512, 128};
    gemmP<false, false, 2, 2, EpiBF16Pair><<<dim3(8, 2, 32), 256, 0, stream>>>(g, e);
  }
  // ---- S[b][l'][l] = fv_l . fa_v  (64x64 tile, 128 blocks)
  {
    GemmArgs g{}; g.Ah = fvl_h; g.Alo = fvl_l; g.Bh = fav_h; g.Blo = fav_l;
    g.K = 512; g.Mld = 77; g.Nld = 128; g.lda = 512; g.ldb = 512;
    g.sA = 77 * 512; g.sB = 128 * 512;
    EpiBF16Pair e{s_h, s_l, nullptr, 128 * 128, 128, 128};
    gemmP<false, false, 2, 2, EpiBF16Pair><<<dim3(2, 2, 32), 256, 0, stream>>>(g, e);
  }
  // ---- T_t[b][o][l'] = (S @ W_m)^T  (64x64 tile, 768 blocks; zero l'>=77)
  {
    GemmArgs g{}; g.Ah = s_h; g.Alo = s_l; g.Bh = wm_h; g.Blo = wm_l;
    g.K = 128; g.Mld = 128; g.Nld = 768; g.lda = 128; g.ldb = 128;
    g.sA = 128 * 128; g.sB = 0;
    EpiTransT e{tt_h, tt_l};
    gemmP<false, false, 2, 2, EpiTransT><<<dim3(12, 2, 32), 256, 0, stream>>>(g, e);
  }
  // ---- OUT: out[b][v][o] = P2t @ T_t + b_m  (M=1024, N=768, K=128)
  {
    GemmArgs g{}; g.Ah = p2t_h; g.Alo = p2t_l; g.Bh = tt_h; g.Blo = tt_l;
    g.K = 128; g.Mld = 1024; g.Nld = 768; g.lda = 128; g.ldb = 128;
    g.sA = 1024 * 128; g.sB = 768 * 128;
    EpiOutB e{(float*)d_out, b_m};
    gemmP<false, false, 4, 4, EpiOutB><<<dim3(6, 8, 32), 256, 0, stream>>>(g, e);
  }
  (void)in_sizes; (void)n_in; (void)out_size;
}

// Round 8
// 535.820 us; speedup vs baseline: 1.2137x; 1.0230x over previous
//
#include <hip/hip_runtime.h>

// ---------------------------------------------------------------------------
// DenseLanguageGuidanceModule on MI355X (gfx950)
// bf16 hi/lo split GEMMs (x3 MFMA, fp32 accumulate) for ~fp32 accuracy.
// Round 8: pre-split fv/fl to bf16 pairs once (32us HBM pass) so the GEMM
// hot loop is pure DMA staging + MFMA (no in-loop split VALU). All GEMMs use
// the round-5 dbuf pipeline. Workspace overlay keeps total ~256MB.
// ---------------------------------------------------------------------------

using s16x8  = __attribute__((ext_vector_type(8))) short;
using f32x4v = __attribute__((ext_vector_type(4))) float;

__device__ __forceinline__ unsigned short f2bf(float f) {
  unsigned int u = __float_as_uint(f);
  u += 0x7fffu + ((u >> 16) & 1u);     // RNE
  return (unsigned short)(u >> 16);
}
__device__ __forceinline__ float bf2f(unsigned short h) {
  return __uint_as_float(((unsigned int)h) << 16);
}
__device__ __forceinline__ void split2(float v, unsigned short &hh, unsigned short &ll) {
  hh = f2bf(v);
  ll = f2bf(v - bf2f(hh));
}

// async global->LDS, 16B per lane; LDS dest is wave-uniform base + lane*16
__device__ __forceinline__ void gload16(const unsigned short* g, unsigned short* l) {
  __builtin_amdgcn_global_load_lds(
      (const __attribute__((address_space(1))) unsigned int*)(const void*)g,
      (__attribute__((address_space(3))) unsigned int*)(void*)l,
      16, 0, 0);
}

// ---------------- fp32 -> bf16 hi/lo pair ----------------
__global__ __launch_bounds__(256) void split_f32(const float* __restrict__ x,
                                                 unsigned short* __restrict__ h,
                                                 unsigned short* __restrict__ lo,
                                                 long n4) {
  long i = (long)blockIdx.x * 256 + threadIdx.x;
  if (i >= n4) return;
  float4 v = ((const float4*)x)[i];
  ushort4 H, L;
  split2(v.x, H.x, L.x); split2(v.y, H.y, L.y);
  split2(v.z, H.z, L.z); split2(v.w, H.w, L.w);
  ((ushort4*)h)[i]  = H;
  ((ushort4*)lo)[i] = L;
}

// ---- fused weight prep: transpose W[K][N] -> Wt[N][Kpad] bf16 pair --------
struct PrepSeg { const float* W; unsigned short* Wh; unsigned short* Wl;
                 int K, N, Kpad, ntx, tOff; };
struct PrepArgs { PrepSeg s[5]; };

__global__ __launch_bounds__(256) void prep_all(PrepArgs pa) {
  __shared__ float tile[32][33];
  int bid = blockIdx.x;
  int si = 0;
  #pragma unroll
  for (int i = 1; i < 5; ++i) if (bid >= pa.s[i].tOff) si = i;
  PrepSeg sg = pa.s[si];
  int local = bid - sg.tOff;
  int nb = (local % sg.ntx) * 32, kb = (local / sg.ntx) * 32;
  int tx = threadIdx.x & 31, ty = threadIdx.x >> 5;   // 32 x 8
  #pragma unroll
  for (int i = 0; i < 32; i += 8) {
    int k = kb + ty + i, n = nb + tx;
    tile[ty + i][tx] = (k < sg.K && n < sg.N) ? sg.W[(long)k * sg.N + n] : 0.f;
  }
  __syncthreads();
  #pragma unroll
  for (int i = 0; i < 32; i += 8) {
    int n = nb + ty + i, k = kb + tx;
    if (n < sg.N && k < sg.Kpad) {
      unsigned short hh, ll;
      split2(tile[tx][ty + i], hh, ll);
      sg.Wh[(long)n * sg.Kpad + k] = hh;
      sg.Wl[(long)n * sg.Kpad + k] = ll;
    }
  }
}

// ---------------- generic NT GEMM, bf16 hi/lo x3, 2-phase dbuf --------------
// C[m][n] = sum_k A[m][k] * Bt[n][k]; both operands pre-split bf16 pairs.
// Tile (MI*32) x (NJ*32), BK=32, 256 threads (4 waves 2x2).
// All staging via global_load_lds (linear LDS dest, XOR on SOURCE chunk).
// LDS dbuf: MI4/NJ4 = 64KB (2 blocks/CU), MI2/NJ2 = 32KB.
struct GemmArgs {
  const unsigned short *Ah, *Alo, *Bh, *Blo;
  int K;            // multiple of 32
  int Mld, Nld;     // row clamp bounds
  int lda, ldb;     // row strides (elements)
  long long sA, sB; // batch strides (elements)
};

template <bool SWZ, int MI, int NJ, class Epi>
__global__ __launch_bounds__(256, 2) void gemmD(GemmArgs g, Epi epi) {
  constexpr int ASZ = MI * 1024;       // shorts per A component per buffer
  constexpr int BSZ = NJ * 1024;
  constexpr int BUF = 2 * ASZ + 2 * BSZ;
  __shared__ __align__(16) unsigned short sm[2 * BUF];

  int bidx = blockIdx.x, bidy = blockIdx.y;
  if constexpr (SWZ) {   // XCD-contiguous remap (requires nwg % 8 == 0)
    int nx = gridDim.x;
    int nwg = nx * gridDim.y;
    int orig = bidx + bidy * nx;
    int swz = (orig & 7) * (nwg >> 3) + (orig >> 3);
    bidx = swz % nx; bidy = swz / nx;
  }

  const int t    = threadIdx.x;
  const int b    = blockIdx.z;
  const int m0   = bidy * (MI * 32);
  const int n0   = bidx * (NJ * 32);
  const int lane = t & 63;
  const int w    = t >> 6;
  const int wr   = (w >> 1) * (MI * 16);
  const int wc   = (w & 1) * (NJ * 16);

  const long long aBase = (long long)b * g.sA;
  const long long bBase = (long long)b * g.sB;

  // ---- DMA staging coords ----
  const int clk = lane & 3;
  const int rwB = (NJ == 4) ? ((w << 5) + (lane >> 2)) : ((w << 4) + (lane >> 2));
  const int sckB = ((clk ^ ((rwB >> 1) & 3)) << 3);
  int br0 = n0 + rwB;      if (br0 > g.Nld - 1) br0 = g.Nld - 1;
  int br1 = n0 + rwB + 16; if (br1 > g.Nld - 1) br1 = g.Nld - 1;
  const long long bR0d = bBase + (long long)br0 * g.ldb + sckB;
  const long long bR1d = bBase + (long long)br1 * g.ldb + sckB;
  const int dB0 = w * ((NJ == 4) ? 1024 : 512);
  const int dB1 = dB0 + 512;                           // NJ==4 only
  const int rwA = (MI == 4) ? ((w << 5) + (lane >> 2)) : ((w << 4) + (lane >> 2));
  const int sckA = ((clk ^ ((rwA >> 1) & 3)) << 3);
  int arD0 = m0 + rwA;      if (arD0 > g.Mld - 1) arD0 = g.Mld - 1;
  int arD1 = m0 + rwA + 16; if (arD1 > g.Mld - 1) arD1 = g.Mld - 1;
  const long long aR0d = aBase + (long long)arD0 * g.lda + sckA;
  const long long aR1d = aBase + (long long)arD1 * g.lda + sckA;
  const int dA0 = w * ((MI == 4) ? 1024 : 512);
  const int dA1 = dA0 + 512;                           // MI==4 only

  // read-fragment offsets (constant; add buf base)
  int roffA[MI], roffB[NJ];
  #pragma unroll
  for (int i = 0; i < MI; ++i) {
    int row = wr + i * 16 + (lane & 15);
    int ch  = lane >> 4;
    roffA[i] = row * 32 + ((ch ^ ((row >> 1) & 3)) << 3);
  }
  #pragma unroll
  for (int j = 0; j < NJ; ++j) {
    int row = wc + j * 16 + (lane & 15);
    int ch  = lane >> 4;
    roffB[j] = row * 32 + ((ch ^ ((row >> 1) & 3)) << 3);
  }

  f32x4v acc[MI][NJ];
  #pragma unroll
  for (int i = 0; i < MI; ++i)
    #pragma unroll
    for (int j = 0; j < NJ; ++j)
      #pragma unroll
      for (int r = 0; r < 4; ++r) acc[i][j][r] = 0.f;

  auto issueDMA = [&](int k0, int p) {
    unsigned short* bb = sm + p * BUF;
    gload16(g.Bh  + (bR0d + k0), bb + 2 * ASZ + dB0);
    gload16(g.Blo + (bR0d + k0), bb + 2 * ASZ + BSZ + dB0);
    if constexpr (NJ == 4) {
      gload16(g.Bh  + (bR1d + k0), bb + 2 * ASZ + dB1);
      gload16(g.Blo + (bR1d + k0), bb + 2 * ASZ + BSZ + dB1);
    }
    gload16(g.Ah  + (aR0d + k0), bb + dA0);
    gload16(g.Alo + (aR0d + k0), bb + ASZ + dA0);
    if constexpr (MI == 4) {
      gload16(g.Ah  + (aR1d + k0), bb + dA1);
      gload16(g.Alo + (aR1d + k0), bb + ASZ + dA1);
    }
  };

  // prologue: stage tile 0 into buf 0
  issueDMA(0, 0);
  int p = 0;
  const int nkt = g.K >> 5;
  for (int kt = 0; kt < nkt; ++kt) {
    asm volatile("s_waitcnt vmcnt(0)" ::: "memory");  // tile-kt DMA landed
    __syncthreads();
    if (kt + 1 < nkt) issueDMA((kt + 1) << 5, p ^ 1); // flies under compute
    unsigned short* base = sm + p * BUF;
    s16x8 ah[MI], al[MI], bh[NJ], bl[NJ];
    #pragma unroll
    for (int i = 0; i < MI; ++i) {
      ah[i] = *(const s16x8*)(base + roffA[i]);
      al[i] = *(const s16x8*)(base + ASZ + roffA[i]);
    }
    #pragma unroll
    for (int j = 0; j < NJ; ++j) {
      bh[j] = *(const s16x8*)(base + 2 * ASZ + roffB[j]);
      bl[j] = *(const s16x8*)(base + 2 * ASZ + BSZ + roffB[j]);
    }
    #pragma unroll
    for (int i = 0; i < MI; ++i)
      #pragma unroll
      for (int j = 0; j < NJ; ++j) {
        acc[i][j] = __builtin_amdgcn_mfma_f32_16x16x32_bf16(ah[i], bh[j], acc[i][j], 0, 0, 0);
        acc[i][j] = __builtin_amdgcn_mfma_f32_16x16x32_bf16(ah[i], bl[j], acc[i][j], 0, 0, 0);
        acc[i][j] = __builtin_amdgcn_mfma_f32_16x16x32_bf16(al[i], bh[j], acc[i][j], 0, 0, 0);
      }
    p ^= 1;
  }
  // epilogue: D row=(lane>>4)*4+r, col=lane&15
  #pragma unroll
  for (int i = 0; i < MI; ++i)
    #pragma unroll
    for (int j = 0; j < NJ; ++j) {
      int mm = m0 + wr + i * 16 + ((lane >> 4) << 2);
      int nn = n0 + wc + j * 16 + (lane & 15);
      epi(b, mm, nn, acc[i][j]);
    }
}

// ---------------- epilogues ----------------
struct EpiBF16Pair {   // out[b][m][n] bf16 hi/lo pair (+optional bias)
  unsigned short *h, *lo; const float* bias; long long bs; int ld; int Mst;
  __device__ void operator()(int b, int m, int n, f32x4v v) const {
    float bb = bias ? bias[n] : 0.f;
    #pragma unroll
    for (int r = 0; r < 4; ++r) {
      int mm = m + r;
      if (mm < Mst) {
        long long o = (long long)b * bs + (long long)mm * ld + n;
        unsigned short hh, ll;
        split2(v[r] + bb, hh, ll);
        h[o] = hh; lo[o] = ll;
      }
    }
  }
};

struct EpiDualL {      // K1f: n<512 -> fkl[m][n]; n>=512 -> fvl[m][n-512]
  unsigned short *kh, *kl, *vh, *vl; const float *bk, *bv;
  __device__ void operator()(int, int m, int n, f32x4v v) const {
    bool lo512 = n < 512;
    float bb = lo512 ? bk[n] : bv[n - 512];
    int nn = lo512 ? n : n - 512;
    unsigned short* H = lo512 ? kh : vh;
    unsigned short* L = lo512 ? kl : vl;
    #pragma unroll
    for (int r = 0; r < 4; ++r) {
      int mm = m + r;
      if (mm < 2464) {
        long long o = (long long)mm * 512 + nn;
        unsigned short hh, ll;
        split2(v[r] + bb, hh, ll);
        H[o] = hh; L[o] = ll;
      }
    }
  }
};

struct EpiDualV {      // K2f: n<512 -> fkv[m][n]; n>=512 -> fvvT[b2][n-512][v]
  unsigned short *kh, *kl, *vh, *vl; const float *bk, *bv;
  __device__ void operator()(int, int m, int n, f32x4v v) const {
    if (n < 512) {
      float bb = bk[n];
      #pragma unroll
      for (int r = 0; r < 4; ++r) {
        long long o = (long long)(m + r) * 512 + n;
        unsigned short hh, ll;
        split2(v[r] + bb, hh, ll);
        kh[o] = hh; kl[o] = ll;
      }
    } else {
      int b2 = m >> 10, vv = m & 1023;
      float bb = bv[n - 512];
      ushort4 H, L;
      split2(v[0] + bb, H.x, L.x); split2(v[1] + bb, H.y, L.y);
      split2(v[2] + bb, H.z, L.z); split2(v[3] + bb, H.w, L.w);
      long long o = ((long long)b2 * 512 + (n - 512)) * 1024 + vv;
      *(ushort4*)(vh + o) = H;
      *(ushort4*)(vl + o) = L;
    }
  }
};

struct EpiScore {      // K3: a_raw[b][m][n] fp32, scaled, m<77
  float* out;
  __device__ void operator()(int b, int m, int n, f32x4v v) const {
    #pragma unroll
    for (int r = 0; r < 4; ++r) {
      int mm = m + r;
      if (mm < 77)
        out[((long long)b * 77 + mm) * 1024 + n] = v[r] * 0.04419417382415922f;
    }
  }
};

struct EpiTransT {     // T-gemm: T_t[b][o=n][l=m+r], zero l>=77
  unsigned short *h, *lo;
  __device__ void operator()(int b, int m, int n, f32x4v v) const {
    #pragma unroll
    for (int r = 0; r < 4; ++r) {
      int mm = m + r;
      float val = (mm < 77) ? v[r] : 0.f;
      long long o = (long long)b * 98304 + (long long)n * 128 + mm;
      unsigned short hh, ll;
      split2(val, hh, ll);
      h[o] = hh; lo[o] = ll;
    }
  }
};

struct EpiOutB {       // OUT: d_out[b*1024+m][768] fp32 + b_m
  float* out; const float* bias;
  __device__ void operator()(int b, int m, int n, f32x4v v) const {
    float bb = bias[n];
    #pragma unroll
    for (int r = 0; r < 4; ++r)
      out[(long long)(b * 1024 + m + r) * 768 + n] = v[r] + bb;
  }
};

// ---------------- softmax over Nv (rows of a_raw) ----------------
__global__ __launch_bounds__(256) void softmax_rows(const float* __restrict__ a,
                                                    unsigned short* __restrict__ Ph,
                                                    unsigned short* __restrict__ Plo) {
  long row = blockIdx.x;                 // (b*77+l)
  const float* src = a + row * 1024;
  int t = threadIdx.x;
  float4 x = ((const float4*)src)[t];
  float mx = fmaxf(fmaxf(x.x, x.y), fmaxf(x.z, x.w));
  #pragma unroll
  for (int o = 32; o; o >>= 1) mx = fmaxf(mx, __shfl_xor(mx, o));
  __shared__ float red[4], red2[4];
  int w = t >> 6;
  if ((t & 63) == 0) red[w] = mx;
  __syncthreads();
  mx = fmaxf(fmaxf(red[0], red[1]), fmaxf(red[2], red[3]));
  float e0 = __expf(x.x - mx), e1 = __expf(x.y - mx);
  float e2 = __expf(x.z - mx), e3 = __expf(x.w - mx);
  float s = e0 + e1 + e2 + e3;
  #pragma unroll
  for (int o = 32; o; o >>= 1) s += __shfl_xor(s, o);
  if ((t & 63) == 0) red2[w] = s;
  __syncthreads();
  s = red2[0] + red2[1] + red2[2] + red2[3];
  float inv = 1.f / s;
  ushort4 H, L;
  split2(e0 * inv, H.x, L.x); split2(e1 * inv, H.y, L.y);
  split2(e2 * inv, H.z, L.z); split2(e3 * inv, H.w, L.w);
  long o = row * 1024 + (long)t * 4;
  *(ushort4*)(Ph + o)  = H;
  *(ushort4*)(Plo + o) = L;
}

// -------- softmax over Nl (cols), writes P2t[b][v][128] (k>=77 zero) --------
__global__ __launch_bounds__(128) void softmax_cols(const float* __restrict__ a,
                                                    unsigned short* __restrict__ Ph,
                                                    unsigned short* __restrict__ Plo) {
  __shared__ float tile[77 * 129];
  __shared__ float inv[128];
  int t = threadIdx.x;                  // 0..127
  int c = blockIdx.x;                   // v-chunk (of 128)
  int b = blockIdx.y;
  const float* src = a + (long)b * 77 * 1024 + c * 128;
  for (int r = 0; r < 77; ++r) tile[r * 129 + t] = src[(long)r * 1024 + t];
  __syncthreads();
  float mx = -1e30f;
  for (int r = 0; r < 77; ++r) mx = fmaxf(mx, tile[r * 129 + t]);
  float s = 0.f;
  for (int r = 0; r < 77; ++r) {
    float e = __expf(tile[r * 129 + t] - mx);
    tile[r * 129 + t] = e;
    s += e;
  }
  inv[t] = 1.f / s;
  __syncthreads();
  unsigned short* dh = Ph  + ((long)b * 1024 + c * 128) * 128;
  unsigned short* dl = Plo + ((long)b * 1024 + c * 128) * 128;
  for (int vb = 0; vb < 128; vb += 2) {
    int v = vb + (t >> 6);
    int k = (t & 63) * 2;
    float iv = inv[v];
    float p0 = (k     < 77) ? tile[k * 129 + v] * iv       : 0.f;
    float p1 = (k + 1 < 77) ? tile[(k + 1) * 129 + v] * iv : 0.f;
    ushort2 H, L;
    split2(p0, H.x, L.x); split2(p1, H.y, L.y);
    *(ushort2*)(dh + (long)v * 128 + k) = H;
    *(ushort2*)(dl + (long)v * 128 + k) = L;
  }
}

// ---------------------------------------------------------------------------
extern "C" void kernel_launch(void* const* d_in, const int* in_sizes, int n_in,
                              void* d_out, int out_size, void* d_ws, size_t ws_size,
                              hipStream_t stream) {
  const float* fv   = (const float*)d_in[0];
  const float* fl   = (const float*)d_in[1];
  const float* W_vk = (const float*)d_in[2];
  const float* b_vk = (const float*)d_in[3];
  const float* W_vv = (const float*)d_in[4];
  const float* b_vv = (const float*)d_in[5];
  const float* W_lk = (const float*)d_in[6];
  const float* b_lk = (const float*)d_in[7];
  const float* W_lv = (const float*)d_in[8];
  const float* b_lv = (const float*)d_in[9];
  const float* W_m  = (const float*)d_in[10];
  const float* b_m  = (const float*)d_in[11];

  char* base = (char*)d_ws;
  size_t off = 0;
  auto take = [&](size_t bytes) -> char* {
    char* p = base + off;
    off = (off + bytes + 255) & ~(size_t)255;
    return p;
  };

  // weights (concatenated, pre-transposed, bf16 pairs)
  unsigned short* wcatv_h = (unsigned short*)take(1572864);  // [1024][768]
  unsigned short* wcatv_l = (unsigned short*)take(1572864);
  unsigned short* wcatl_h = (unsigned short*)take(1048576);  // [1024][512]
  unsigned short* wcatl_l = (unsigned short*)take(1048576);
  unsigned short* wm_h    = (unsigned short*)take(196608);   // [768][128]
  unsigned short* wm_l    = (unsigned short*)take(196608);
  // pre-split activations + persistent intermediates
  unsigned short* fl_h   = (unsigned short*)take(2523136);   // [2464][512]
  unsigned short* fl_l   = (unsigned short*)take(2523136);
  unsigned short* fkl_h  = (unsigned short*)take(2523136);   // [2464][512]
  unsigned short* fkl_l  = (unsigned short*)take(2523136);
  unsigned short* fvl_h  = (unsigned short*)take(2523136);   // [2464][512]
  unsigned short* fvl_l  = (unsigned short*)take(2523136);
  unsigned short* fkv_h  = (unsigned short*)take(33554432);  // [32768][512]
  unsigned short* fkv_l  = (unsigned short*)take(33554432);
  unsigned short* fvvT_h = (unsigned short*)take(33554432);  // [32][512][1024]
  unsigned short* fvvT_l = (unsigned short*)take(33554432);
  // Region F: fv pair (dead after K2f) | post-K2f intermediates (60MB < 100MB)
  char* regF = take(100663296);
  unsigned short* fv_h = (unsigned short*)regF;               // [32768][768]
  unsigned short* fv_l = (unsigned short*)(regF + 50331648);
  float*          araw = (float*)regF;                        // [32][77][1024]
  unsigned short* p1_h = (unsigned short*)(regF + 10092544);  // [2464][1024]
  unsigned short* p1_l = (unsigned short*)(regF + 15138816);
  unsigned short* p2t_h= (unsigned short*)(regF + 20185088);  // [32][1024][128]
  unsigned short* p2t_l= (unsigned short*)(regF + 28573696);
  unsigned short* fav_h= (unsigned short*)(regF + 36962304);  // [32][128][512]
  unsigned short* fav_l= (unsigned short*)(regF + 41156608);
  unsigned short* s_h  = (unsigned short*)(regF + 45350912);  // [32][128][128]
  unsigned short* s_l  = (unsigned short*)(regF + 46399488);
  unsigned short* tt_h = (unsigned short*)(regF + 47448064);  // [32][768][128]
  unsigned short* tt_l = (unsigned short*)(regF + 53739520);

  if (off > ws_size) return;  // workspace too small: fail loudly via mismatch

  // ---- pre-split activations ----
  split_f32<<<24576, 256, 0, stream>>>(fv, fv_h, fv_l, 6291456);  // 32768*768/4
  split_f32<<<1232, 256, 0, stream>>>(fl, fl_h, fl_l, 315392);    // 2464*512/4

  // ---- prep weights (one fused launch, 1376 tiles) ----
  {
    PrepArgs pa;
    pa.s[0] = {W_vk, wcatv_h,               wcatv_l,               768, 512, 768, 16, 0};
    pa.s[1] = {W_vv, wcatv_h + 512 * 768,   wcatv_l + 512 * 768,   768, 512, 768, 16, 384};
    pa.s[2] = {W_lk, wcatl_h,               wcatl_l,               512, 512, 512, 16, 768};
    pa.s[3] = {W_lv, wcatl_h + 512 * 512,   wcatl_l + 512 * 512,   512, 512, 512, 16, 1024};
    pa.s[4] = {W_m,  wm_h,                  wm_l,                   77, 768, 128, 24, 1280};
    prep_all<<<1376, 256, 0, stream>>>(pa);
  }

  // ---- K1f: [fk_l | fv_l] = fl @ [W_lk | W_lv] + bias  (M=2464, N=1024, K=512)
  {
    GemmArgs g{}; g.Ah = fl_h; g.Alo = fl_l; g.Bh = wcatl_h; g.Blo = wcatl_l;
    g.K = 512; g.Mld = 2464; g.Nld = 1024; g.lda = 512; g.ldb = 512; g.sA = 0; g.sB = 0;
    EpiDualL e{fkl_h, fkl_l, fvl_h, fvl_l, b_lk, b_lv};
    gemmD<false, 4, 4, EpiDualL><<<dim3(8, 20, 1), 256, 0, stream>>>(g, e);
  }
  // ---- K2f: [fk_v | fv_v^T] = fv @ [W_vk | W_vv] + bias (M=32768, N=1024, K=768)
  {
    GemmArgs g{}; g.Ah = fv_h; g.Alo = fv_l; g.Bh = wcatv_h; g.Blo = wcatv_l;
    g.K = 768; g.Mld = 32768; g.Nld = 1024; g.lda = 768; g.ldb = 768; g.sA = 0; g.sB = 0;
    EpiDualV e{fkv_h, fkv_l, fvvT_h, fvvT_l, b_vk, b_vv};
    gemmD<true, 4, 4, EpiDualV><<<dim3(8, 256, 1), 256, 0, stream>>>(g, e);
  }
  // ---- K3: a_raw[b][l][v] = fk_l . fk_v / sqrt(512)  (64x64 tile, 1024 blocks)
  {
    GemmArgs g{}; g.Ah = fkl_h; g.Alo = fkl_l; g.Bh = fkv_h; g.Blo = fkv_l;
    g.K = 512; g.Mld = 77; g.Nld = 1024; g.lda = 512; g.ldb = 512;
    g.sA = 77 * 512; g.sB = 1024 * 512;
    EpiScore e{araw};
    gemmD<false, 2, 2, EpiScore><<<dim3(16, 2, 32), 256, 0, stream>>>(g, e);
  }
  // ---- softmaxes ----
  softmax_rows<<<2464, 256, 0, stream>>>(araw, p1_h, p1_l);
  softmax_cols<<<dim3(8, 32), 128, 0, stream>>>(araw, p2t_h, p2t_l);
  // ---- K5: fa_v[b][l][e] = P1 @ fv_v (via fv_vT)  (64x64 tile, 512 blocks)
  {
    GemmArgs g{}; g.Ah = p1_h; g.Alo = p1_l; g.Bh = fvvT_h; g.Blo = fvvT_l;
    g.K = 1024; g.Mld = 77; g.Nld = 512; g.lda = 1024; g.ldb = 1024;
    g.sA = 77 * 1024; g.sB = 512 * 1024;
    EpiBF16Pair e{fav_h, fav_l, nullptr, 128 * 512, 512, 128};
    gemmD<false, 2, 2, EpiBF16Pair><<<dim3(8, 2, 32), 256, 0, stream>>>(g, e);
  }
  // ---- S[b][l'][l] = fv_l . fa_v  (64x64 tile, 128 blocks)
  {
    GemmArgs g{}; g.Ah = fvl_h; g.Alo = fvl_l; g.Bh = fav_h; g.Blo = fav_l;
    g.K = 512; g.Mld = 77; g.Nld = 128; g.lda = 512; g.ldb = 512;
    g.sA = 77 * 512; g.sB = 128 * 512;
    EpiBF16Pair e{s_h, s_l, nullptr, 128 * 128, 128, 128};
    gemmD<false, 2, 2, EpiBF16Pair><<<dim3(2, 2, 32), 256, 0, stream>>>(g, e);
  }
  // ---- T_t[b][o][l'] = (S @ W_m)^T  (64x64 tile, 768 blocks; zero l'>=77)
  {
    GemmArgs g{}; g.Ah = s_h; g.Alo = s_l; g.Bh = wm_h; g.Blo = wm_l;
    g.K = 128; g.Mld = 128; g.Nld = 768; g.lda = 128; g.ldb = 128;
    g.sA = 128 * 128; g.sB = 0;
    EpiTransT e{tt_h, tt_l};
    gemmD<false, 2, 2, EpiTransT><<<dim3(12, 2, 32), 256, 0, stream>>>(g, e);
  }
  // ---- OUT: out[b][v][o] = P2t @ T_t + b_m  (M=1024, N=768, K=128)
  {
    GemmArgs g{}; g.Ah = p2t_h; g.Alo = p2t_l; g.Bh = tt_h; g.Blo = tt_l;
    g.K = 128; g.Mld = 1024; g.Nld = 768; g.lda = 128; g.ldb = 128;
    g.sA = 1024 * 128; g.sB = 768 * 128;
    EpiOutB e{(float*)d_out, b_m};
    gemmD<false, 4, 4, EpiOutB><<<dim3(6, 8, 32), 256, 0, stream>>>(g, e);
  }
  (void)in_sizes; (void)n_in; (void)out_size;
}